// Round 1
// baseline (5774.064 us; speedup 1.0000x reference)
//
#include <hip/hip_runtime.h>
#include <hip/hip_bf16.h>

// Problem constants (fixed by the reference file)
#define NC 8192      // n_clusters
#define SDIM 32
#define ADIM 4
#define XDIM 36      // SD + A
#define HDIM 64
// Workspace layout (floats):
//   [0*NC .. 1*NC)   counts
//   [1*NC .. 2*NC)   wsum
//   [(2+d)*NC ...)   sum arch_state[d]        d=0..3
//   [(6+d)*NC ...)   sum w*arch_state[d]
//   [(10+d)*NC ...)  sum arch_state[d]^2
//   [14*NC .. +10)   global sums: wc_sum, nvalid, sum wc*agg[4], sum valid*agg[4]

__device__ __forceinline__ float sigmoidf_(float t) {
    return 1.0f / (1.0f + __expf(-t));
}

__global__ __launch_bounds__(256) void cell_kernel(
    const float* __restrict__ cell_state,
    const float* __restrict__ arch_state,
    const float* __restrict__ energy,
    const float* __restrict__ phi_local,
    const float* __restrict__ W1,
    const float* __restrict__ b1,
    const float* __restrict__ W2,
    const float* __restrict__ b2,
    const int*   __restrict__ seg_ids,
    float* __restrict__ ws,
    int n)
{
    __shared__ float sW1[XDIM * HDIM];
    __shared__ float sb1[HDIM];
    __shared__ float sW2[HDIM];
    __shared__ float sb2;
    const int tid = threadIdx.x;
    for (int i = tid; i < XDIM * HDIM; i += 256) sW1[i] = W1[i];
    if (tid < HDIM) { sb1[tid] = b1[tid]; sW2[tid] = W2[tid]; }
    if (tid == 0) sb2 = b2[0];
    __syncthreads();

    const int gid = blockIdx.x * 256 + tid;
    const bool active = gid < n;
    const int lid = active ? gid : (n - 1);   // clamped for safe loads

    // ---- load x = concat(cell_state, arch_state) ----
    float x[XDIM];
    const float4* cs4 = reinterpret_cast<const float4*>(cell_state + (size_t)lid * SDIM);
    #pragma unroll
    for (int q = 0; q < SDIM / 4; ++q) {
        float4 v = cs4[q];
        x[q * 4 + 0] = v.x; x[q * 4 + 1] = v.y;
        x[q * 4 + 2] = v.z; x[q * 4 + 3] = v.w;
    }
    const float4 av = reinterpret_cast<const float4*>(arch_state)[lid];
    x[32] = av.x; x[33] = av.y; x[34] = av.z; x[35] = av.w;

    // ---- MLP: h = relu(x@W1 + b1); base = sigmoid(h@W2 + b2) ----
    float h[HDIM];
    #pragma unroll
    for (int j = 0; j < HDIM; ++j) h[j] = sb1[j];
    #pragma unroll
    for (int k = 0; k < XDIM; ++k) {
        const float xk = x[k];
        #pragma unroll
        for (int j = 0; j < HDIM; ++j)
            h[j] = __builtin_fmaf(xk, sW1[k * HDIM + j], h[j]);
    }
    float acc = sb2;
    #pragma unroll
    for (int j = 0; j < HDIM; ++j) acc += fmaxf(h[j], 0.0f) * sW2[j];
    const float base = sigmoidf_(acc);

    const float e = energy[lid];
    const float p = phi_local[lid];
    const float ep = e * p;
    const float imp = fminf(fmaxf(base * ep, 0.01f), 1.0f);
    const float w = imp * ep;

    int s = active ? seg_ids[lid] : -1;

    // ---- 14 per-cell values for the segmented reduction ----
    float v[14];
    const float m = active ? 1.0f : 0.0f;
    v[0] = m;               // count
    v[1] = m * w;           // wsum
    v[2] = m * av.x; v[3] = m * av.y; v[4] = m * av.z; v[5] = m * av.w;
    v[6] = m * w * av.x; v[7] = m * w * av.y; v[8] = m * w * av.z; v[9] = m * w * av.w;
    v[10] = m * av.x * av.x; v[11] = m * av.y * av.y;
    v[12] = m * av.z * av.z; v[13] = m * av.w * av.w;

    // ---- wave-level segmented inclusive scan (segments = runs of equal s) ----
    const int lane = tid & 63;
    #pragma unroll
    for (int off = 1; off < 64; off <<= 1) {
        const int su = __shfl_up(s, off);
        const bool doadd = (lane >= off) && (su == s);
        #pragma unroll
        for (int i = 0; i < 14; ++i) {
            const float u = __shfl_up(v[i], off);
            if (doadd) v[i] += u;
        }
    }
    const int snext = __shfl_down(s, 1);
    const bool tail = (lane == 63) || (snext != s);
    if (tail && active) {
        #pragma unroll
        for (int i = 0; i < 14; ++i)
            atomicAdd(&ws[(size_t)i * NC + s], v[i]);
    }
}

__global__ __launch_bounds__(256) void cluster_kernel(
    const float* __restrict__ ws,
    const float* __restrict__ Wc1,
    const float* __restrict__ bc1,
    const float* __restrict__ Wc2,
    const float* __restrict__ bc2,
    float* __restrict__ out,
    float* __restrict__ gsum)
{
    const int c = blockIdx.x * 256 + threadIdx.x;

    const float cnt  = ws[c];
    const float wsum = ws[NC + c];
    float sA[4], swA[4], sA2[4];
    #pragma unroll
    for (int d = 0; d < 4; ++d) {
        sA[d]  = ws[(2 + d) * NC + c];
        swA[d] = ws[(6 + d) * NC + c];
        sA2[d] = ws[(10 + d) * NC + c];
    }
    const float safe_cnt = fmaxf(cnt, 1.0f);

    float agg[4];
    if (wsum > 0.0f) {
        const float inv = 1.0f / fmaxf(wsum, 1e-30f);
        #pragma unroll
        for (int d = 0; d < 4; ++d) agg[d] = swA[d] * inv;
    } else {
        const float inv = 1.0f / safe_cnt;
        #pragma unroll
        for (int d = 0; d < 4; ++d) agg[d] = sA[d] * inv;
    }

    float sq = 0.0f;
    #pragma unroll
    for (int d = 0; d < 4; ++d) {
        const float mean = sA[d] / safe_cnt;
        const float s2 = sA2[d] - 2.0f * mean * sA[d] + cnt * mean * mean;
        sq += fmaxf(s2, 0.0f);
    }
    const float var = (cnt >= 2.0f) ? (sq * 0.25f) / fmaxf(cnt - 1.0f, 1.0f) : 0.0f;
    const float phi_c = 1.0f - fminf(1.0f, var * 2.0f);
    const float coh = 1.0f - var;

    float feats[7] = { agg[0], agg[1], agg[2], agg[3],
                       phi_c, coh, fminf(1.0f, cnt * 0.05f) };

    float t = bc2[0];
    #pragma unroll
    for (int j = 0; j < 32; ++j) {
        float hj = bc1[j];
        #pragma unroll
        for (int k = 0; k < 7; ++k)
            hj = __builtin_fmaf(feats[k], Wc1[k * 32 + j], hj);
        t += fmaxf(hj, 0.0f) * Wc2[j];
    }
    const float basec = sigmoidf_(t);
    const float impc = fminf(fmaxf(basec * phi_c, 0.01f), 1.0f);
    const bool valid = cnt > 0.0f;
    const float wc = valid ? impc * cnt : 0.0f;

    // outputs
    #pragma unroll
    for (int d = 0; d < 4; ++d) out[c * 4 + d] = agg[d];
    out[NC * 4 + c] = phi_c;
    out[NC * 5 + c] = coh;

    // global partial sums: wc_sum, nvalid, wc*agg[d], valid*agg[d]
    float r[10];
    r[0] = wc;
    r[1] = valid ? 1.0f : 0.0f;
    #pragma unroll
    for (int d = 0; d < 4; ++d) r[2 + d] = wc * agg[d];
    #pragma unroll
    for (int d = 0; d < 4; ++d) r[6 + d] = valid ? agg[d] : 0.0f;

    #pragma unroll
    for (int off = 32; off > 0; off >>= 1) {
        #pragma unroll
        for (int i = 0; i < 10; ++i) r[i] += __shfl_down(r[i], off);
    }
    if ((threadIdx.x & 63) == 0) {
        #pragma unroll
        for (int i = 0; i < 10; ++i) atomicAdd(&gsum[i], r[i]);
    }
}

__global__ void finalize_kernel(const float* __restrict__ gsum,
                                float* __restrict__ out)
{
    if (threadIdx.x == 0 && blockIdx.x == 0) {
        const float wcs = gsum[0];
        const float nv = fmaxf(gsum[1], 1.0f);
        #pragma unroll
        for (int d = 0; d < 4; ++d) {
            const float num = (wcs > 0.0f) ? gsum[2 + d] / fmaxf(wcs, 1e-30f)
                                           : gsum[6 + d] / nv;
            out[NC * 6 + d] = num;
        }
    }
}

extern "C" void kernel_launch(void* const* d_in, const int* in_sizes, int n_in,
                              void* d_out, int out_size, void* d_ws, size_t ws_size,
                              hipStream_t stream) {
    const float* cell_state = (const float*)d_in[0];
    const float* arch_state = (const float*)d_in[1];
    const float* energy     = (const float*)d_in[2];
    const float* phi_local  = (const float*)d_in[3];
    const float* W1  = (const float*)d_in[4];
    const float* b1  = (const float*)d_in[5];
    const float* W2  = (const float*)d_in[6];
    const float* b2  = (const float*)d_in[7];
    const float* Wc1 = (const float*)d_in[8];
    const float* bc1 = (const float*)d_in[9];
    const float* Wc2 = (const float*)d_in[10];
    const float* bc2 = (const float*)d_in[11];
    const int* seg   = (const int*)d_in[12];

    const int n = in_sizes[2];  // energy is [N]
    float* ws = (float*)d_ws;
    float* out = (float*)d_out;

    // zero accumulators (d_ws is poisoned, never re-poisoned between replays)
    const size_t ws_floats = (size_t)14 * NC + 16;
    hipMemsetAsync(d_ws, 0, ws_floats * sizeof(float), stream);

    const int nb = (n + 255) / 256;
    cell_kernel<<<nb, 256, 0, stream>>>(cell_state, arch_state, energy, phi_local,
                                        W1, b1, W2, b2, seg, ws, n);
    cluster_kernel<<<NC / 256, 256, 0, stream>>>(ws, Wc1, bc1, Wc2, bc2,
                                                 out, ws + (size_t)14 * NC);
    finalize_kernel<<<1, 64, 0, stream>>>(ws + (size_t)14 * NC, out);
}

// Round 2
// 4122.635 us; speedup vs baseline: 1.4006x; 1.4006x over previous
//
#include <hip/hip_runtime.h>
#include <hip/hip_bf16.h>

// Problem constants (fixed by the reference file)
#define NC 8192      // n_clusters
#define SDIM 32
#define ADIM 4
#define XDIM 36      // SD + A
#define HDIM 64
#define JG 16        // hidden-layer blocking: 4 groups of 16 accumulators
// Workspace layout (floats):
//   [0*NC .. 1*NC)   counts
//   [1*NC .. 2*NC)   wsum
//   [(2+d)*NC ...)   sum arch_state[d]        d=0..3
//   [(6+d)*NC ...)   sum w*arch_state[d]
//   [(10+d)*NC ...)  sum arch_state[d]^2
//   [14*NC .. +10)   global sums: wc_sum, nvalid, sum wc*agg[4], sum valid*agg[4]

__device__ __forceinline__ float sigmoidf_(float t) {
    return 1.0f / (1.0f + __expf(-t));
}

// __launch_bounds__(256, 4): 4 waves/EU min -> VGPR cap 128, >=16 waves/CU.
// Peak live set is ~x[36] + h[16] + misc ~= 80 VGPRs -> no spill.
__global__ __launch_bounds__(256, 4) void cell_kernel(
    const float* __restrict__ cell_state,
    const float* __restrict__ arch_state,
    const float* __restrict__ energy,
    const float* __restrict__ phi_local,
    const float* __restrict__ W1,
    const float* __restrict__ b1,
    const float* __restrict__ W2,
    const float* __restrict__ b2,
    const int*   __restrict__ seg_ids,
    float* __restrict__ ws,
    int n)
{
    __shared__ float sW1[XDIM * HDIM];
    __shared__ float sb1[HDIM];
    __shared__ float sW2[HDIM];
    __shared__ float sb2;
    const int tid = threadIdx.x;
    for (int i = tid; i < XDIM * HDIM; i += 256) sW1[i] = W1[i];
    if (tid < HDIM) { sb1[tid] = b1[tid]; sW2[tid] = W2[tid]; }
    if (tid == 0) sb2 = b2[0];
    __syncthreads();

    const int gid = blockIdx.x * 256 + tid;
    const bool active = gid < n;
    const int lid = active ? gid : (n - 1);   // clamped for safe loads

    // ---- load x = concat(cell_state, arch_state) : stays in 36 VGPRs ----
    float x[XDIM];
    const float4* cs4 = reinterpret_cast<const float4*>(cell_state + (size_t)lid * SDIM);
    #pragma unroll
    for (int q = 0; q < SDIM / 4; ++q) {
        float4 v = cs4[q];
        x[q * 4 + 0] = v.x; x[q * 4 + 1] = v.y;
        x[q * 4 + 2] = v.z; x[q * 4 + 3] = v.w;
    }
    const float4 av = reinterpret_cast<const float4*>(arch_state)[lid];
    x[32] = av.x; x[33] = av.y; x[34] = av.z; x[35] = av.w;

    // ---- MLP, hidden layer blocked in groups of JG accumulators ----
    // h_j = relu(sum_k x_k W1[k][j] + b1[j]);  acc = sum_j h_j * W2[j] + b2
    float acc = sb2;
    #pragma unroll
    for (int j0 = 0; j0 < HDIM; j0 += JG) {
        float h[JG];
        #pragma unroll
        for (int jj = 0; jj < JG; ++jj) h[jj] = sb1[j0 + jj];
        #pragma unroll
        for (int k = 0; k < XDIM; ++k) {
            const float xk = x[k];
            #pragma unroll
            for (int jj = 0; jj < JG; ++jj)
                h[jj] = __builtin_fmaf(xk, sW1[k * HDIM + j0 + jj], h[jj]);
        }
        #pragma unroll
        for (int jj = 0; jj < JG; ++jj)
            acc = __builtin_fmaf(fmaxf(h[jj], 0.0f), sW2[j0 + jj], acc);
    }
    const float base = sigmoidf_(acc);

    const float e = energy[lid];
    const float p = phi_local[lid];
    const float ep = e * p;
    const float imp = fminf(fmaxf(base * ep, 0.01f), 1.0f);
    const float w = imp * ep;

    int s = active ? seg_ids[lid] : -1;

    // ---- 14 per-cell values for the segmented reduction ----
    float v[14];
    const float m = active ? 1.0f : 0.0f;
    v[0] = m;               // count
    v[1] = m * w;           // wsum
    v[2] = m * av.x; v[3] = m * av.y; v[4] = m * av.z; v[5] = m * av.w;
    v[6] = m * w * av.x; v[7] = m * w * av.y; v[8] = m * w * av.z; v[9] = m * w * av.w;
    v[10] = m * av.x * av.x; v[11] = m * av.y * av.y;
    v[12] = m * av.z * av.z; v[13] = m * av.w * av.w;

    // ---- wave-level segmented inclusive scan (segments = runs of equal s) ----
    const int lane = tid & 63;
    #pragma unroll
    for (int off = 1; off < 64; off <<= 1) {
        const int su = __shfl_up(s, off);
        const bool doadd = (lane >= off) && (su == s);
        #pragma unroll
        for (int i = 0; i < 14; ++i) {
            const float u = __shfl_up(v[i], off);
            if (doadd) v[i] += u;
        }
    }
    const int snext = __shfl_down(s, 1);
    const bool tail = (lane == 63) || (snext != s);
    if (tail && active) {
        #pragma unroll
        for (int i = 0; i < 14; ++i)
            atomicAdd(&ws[(size_t)i * NC + s], v[i]);
    }
}

__global__ __launch_bounds__(256) void cluster_kernel(
    const float* __restrict__ ws,
    const float* __restrict__ Wc1,
    const float* __restrict__ bc1,
    const float* __restrict__ Wc2,
    const float* __restrict__ bc2,
    float* __restrict__ out,
    float* __restrict__ gsum)
{
    const int c = blockIdx.x * 256 + threadIdx.x;

    const float cnt  = ws[c];
    const float wsum = ws[NC + c];
    float sA[4], swA[4], sA2[4];
    #pragma unroll
    for (int d = 0; d < 4; ++d) {
        sA[d]  = ws[(2 + d) * NC + c];
        swA[d] = ws[(6 + d) * NC + c];
        sA2[d] = ws[(10 + d) * NC + c];
    }
    const float safe_cnt = fmaxf(cnt, 1.0f);

    float agg[4];
    if (wsum > 0.0f) {
        const float inv = 1.0f / fmaxf(wsum, 1e-30f);
        #pragma unroll
        for (int d = 0; d < 4; ++d) agg[d] = swA[d] * inv;
    } else {
        const float inv = 1.0f / safe_cnt;
        #pragma unroll
        for (int d = 0; d < 4; ++d) agg[d] = sA[d] * inv;
    }

    float sq = 0.0f;
    #pragma unroll
    for (int d = 0; d < 4; ++d) {
        const float mean = sA[d] / safe_cnt;
        const float s2 = sA2[d] - 2.0f * mean * sA[d] + cnt * mean * mean;
        sq += fmaxf(s2, 0.0f);
    }
    const float var = (cnt >= 2.0f) ? (sq * 0.25f) / fmaxf(cnt - 1.0f, 1.0f) : 0.0f;
    const float phi_c = 1.0f - fminf(1.0f, var * 2.0f);
    const float coh = 1.0f - var;

    float feats[7] = { agg[0], agg[1], agg[2], agg[3],
                       phi_c, coh, fminf(1.0f, cnt * 0.05f) };

    float t = bc2[0];
    #pragma unroll
    for (int j = 0; j < 32; ++j) {
        float hj = bc1[j];
        #pragma unroll
        for (int k = 0; k < 7; ++k)
            hj = __builtin_fmaf(feats[k], Wc1[k * 32 + j], hj);
        t += fmaxf(hj, 0.0f) * Wc2[j];
    }
    const float basec = sigmoidf_(t);
    const float impc = fminf(fmaxf(basec * phi_c, 0.01f), 1.0f);
    const bool valid = cnt > 0.0f;
    const float wc = valid ? impc * cnt : 0.0f;

    // outputs
    #pragma unroll
    for (int d = 0; d < 4; ++d) out[c * 4 + d] = agg[d];
    out[NC * 4 + c] = phi_c;
    out[NC * 5 + c] = coh;

    // global partial sums: wc_sum, nvalid, wc*agg[d], valid*agg[d]
    float r[10];
    r[0] = wc;
    r[1] = valid ? 1.0f : 0.0f;
    #pragma unroll
    for (int d = 0; d < 4; ++d) r[2 + d] = wc * agg[d];
    #pragma unroll
    for (int d = 0; d < 4; ++d) r[6 + d] = valid ? agg[d] : 0.0f;

    #pragma unroll
    for (int off = 32; off > 0; off >>= 1) {
        #pragma unroll
        for (int i = 0; i < 10; ++i) r[i] += __shfl_down(r[i], off);
    }
    if ((threadIdx.x & 63) == 0) {
        #pragma unroll
        for (int i = 0; i < 10; ++i) atomicAdd(&gsum[i], r[i]);
    }
}

__global__ void finalize_kernel(const float* __restrict__ gsum,
                                float* __restrict__ out)
{
    if (threadIdx.x == 0 && blockIdx.x == 0) {
        const float wcs = gsum[0];
        const float nv = fmaxf(gsum[1], 1.0f);
        #pragma unroll
        for (int d = 0; d < 4; ++d) {
            const float num = (wcs > 0.0f) ? gsum[2 + d] / fmaxf(wcs, 1e-30f)
                                           : gsum[6 + d] / nv;
            out[NC * 6 + d] = num;
        }
    }
}

extern "C" void kernel_launch(void* const* d_in, const int* in_sizes, int n_in,
                              void* d_out, int out_size, void* d_ws, size_t ws_size,
                              hipStream_t stream) {
    const float* cell_state = (const float*)d_in[0];
    const float* arch_state = (const float*)d_in[1];
    const float* energy     = (const float*)d_in[2];
    const float* phi_local  = (const float*)d_in[3];
    const float* W1  = (const float*)d_in[4];
    const float* b1  = (const float*)d_in[5];
    const float* W2  = (const float*)d_in[6];
    const float* b2  = (const float*)d_in[7];
    const float* Wc1 = (const float*)d_in[8];
    const float* bc1 = (const float*)d_in[9];
    const float* Wc2 = (const float*)d_in[10];
    const float* bc2 = (const float*)d_in[11];
    const int* seg   = (const int*)d_in[12];

    const int n = in_sizes[2];  // energy is [N]
    float* ws = (float*)d_ws;
    float* out = (float*)d_out;

    // zero accumulators (d_ws is poisoned, never re-poisoned between replays)
    const size_t ws_floats = (size_t)14 * NC + 16;
    hipMemsetAsync(d_ws, 0, ws_floats * sizeof(float), stream);

    const int nb = (n + 255) / 256;
    cell_kernel<<<nb, 256, 0, stream>>>(cell_state, arch_state, energy, phi_local,
                                        W1, b1, W2, b2, seg, ws, n);
    cluster_kernel<<<NC / 256, 256, 0, stream>>>(ws, Wc1, bc1, Wc2, bc2,
                                                 out, ws + (size_t)14 * NC);
    finalize_kernel<<<1, 64, 0, stream>>>(ws + (size_t)14 * NC, out);
}

// Round 3
// 136.524 us; speedup vs baseline: 42.2935x; 30.1972x over previous
//
#include <hip/hip_runtime.h>
#include <hip/hip_bf16.h>

// Problem constants (fixed by the reference file)
#define NC 8192      // n_clusters
#define SDIM 32
#define ADIM 4
#define XDIM 36      // SD + A
#define HDIM 64
#define JG 16        // hidden-layer blocking: 4 groups of 16 accumulators
// Workspace layout (floats):
//   [0*NC .. 1*NC)   counts
//   [1*NC .. 2*NC)   wsum
//   [(2+d)*NC ...)   sum arch_state[d]        d=0..3
//   [(6+d)*NC ...)   sum w*arch_state[d]
//   [(10+d)*NC ...)  sum arch_state[d]^2
//   [14*NC .. +10)   global sums: wc_sum, nvalid, sum wc*agg[4], sum valid*agg[4]

__device__ __forceinline__ float sigmoidf_(float t) {
    return 1.0f / (1.0f + __expf(-t));
}

// Native HW fp32 atomic (global_atomic_add_f32), not the default CAS loop.
__device__ __forceinline__ void gadd(float* p, float v) {
    __hip_atomic_fetch_add(p, v, __ATOMIC_RELAXED, __HIP_MEMORY_SCOPE_AGENT);
}

// j0-group loop kept as a REAL loop (code ~8KB, fits 32KB I-cache; full unroll
// was ~40KB and thrashed instruction fetch from L2/HBM for all resident waves).
__global__ __launch_bounds__(256, 4) void cell_kernel(
    const float* __restrict__ cell_state,
    const float* __restrict__ arch_state,
    const float* __restrict__ energy,
    const float* __restrict__ phi_local,
    const float* __restrict__ W1,
    const float* __restrict__ b1,
    const float* __restrict__ W2,
    const float* __restrict__ b2,
    const int*   __restrict__ seg_ids,
    float* __restrict__ ws,
    int n)
{
    __shared__ float sW1[XDIM * HDIM];
    __shared__ float sb1[HDIM];
    __shared__ float sW2[HDIM];
    __shared__ float sb2s[1];
    const int tid = threadIdx.x;
    for (int i = tid; i < XDIM * HDIM; i += 256) sW1[i] = W1[i];
    if (tid < HDIM) { sb1[tid] = b1[tid]; sW2[tid] = W2[tid]; }
    if (tid == 0) sb2s[0] = b2[0];
    __syncthreads();

    const int gid = blockIdx.x * 256 + tid;
    const bool active = gid < n;
    const int lid = active ? gid : (n - 1);   // clamped for safe loads

    // prefetch per-cell scalars early (overlap with MLP)
    const float e = energy[lid];
    const float p = phi_local[lid];
    int s = active ? seg_ids[lid] : -1;

    // ---- load x = concat(cell_state, arch_state) : statically indexed, regs ----
    float x[XDIM];
    const float4* cs4 = reinterpret_cast<const float4*>(cell_state + (size_t)lid * SDIM);
    #pragma unroll
    for (int q = 0; q < SDIM / 4; ++q) {
        float4 v = cs4[q];
        x[q * 4 + 0] = v.x; x[q * 4 + 1] = v.y;
        x[q * 4 + 2] = v.z; x[q * 4 + 3] = v.w;
    }
    const float4 av = reinterpret_cast<const float4*>(arch_state)[lid];
    x[32] = av.x; x[33] = av.y; x[34] = av.z; x[35] = av.w;

    // ---- MLP: hidden layer in 4 looped groups of 16 accumulators ----
    float acc = sb2s[0];
    #pragma unroll 1
    for (int j0 = 0; j0 < HDIM; j0 += JG) {
        float h[JG];
        #pragma unroll
        for (int jj = 0; jj < JG; ++jj) h[jj] = sb1[j0 + jj];
        #pragma unroll
        for (int k = 0; k < XDIM; ++k) {
            const float xk = x[k];
            #pragma unroll
            for (int jj = 0; jj < JG; ++jj)
                h[jj] = __builtin_fmaf(xk, sW1[k * HDIM + j0 + jj], h[jj]);
        }
        #pragma unroll
        for (int jj = 0; jj < JG; ++jj)
            acc = __builtin_fmaf(fmaxf(h[jj], 0.0f), sW2[j0 + jj], acc);
    }
    const float base = sigmoidf_(acc);

    const float ep = e * p;
    const float imp = fminf(fmaxf(base * ep, 0.01f), 1.0f);
    const float m = active ? 1.0f : 0.0f;
    const float w = imp * ep * m;   // mask folded into w

    // ---- 14 named per-cell scalars (no array -> no scratch possible) ----
    float t0 = m,          t1 = w;
    float t2 = m * av.x,   t3 = m * av.y,   t4 = m * av.z,   t5 = m * av.w;
    float t6 = w * av.x,   t7 = w * av.y,   t8 = w * av.z,   t9 = w * av.w;
    float t10 = m * av.x * av.x, t11 = m * av.y * av.y;
    float t12 = m * av.z * av.z, t13 = m * av.w * av.w;

    const int lane = tid & 63;

#define ALL_T(F) F(t0) F(t1) F(t2) F(t3) F(t4) F(t5) F(t6) \
                 F(t7) F(t8) F(t9) F(t10) F(t11) F(t12) F(t13)
#define SCAN_ONE(V) { float u_ = __shfl_up(V, off_); if (da_) V += u_; }
#define SCAN_STEP(OFF) { const int off_ = OFF; \
    const int su_ = __shfl_up(s, off_); \
    const bool da_ = (lane >= off_) && (su_ == s); \
    ALL_T(SCAN_ONE) }

    // wave-level segmented inclusive scan (segments = runs of equal s)
    SCAN_STEP(1); SCAN_STEP(2); SCAN_STEP(4);
    SCAN_STEP(8); SCAN_STEP(16); SCAN_STEP(32);

    const int snext = __shfl_down(s, 1);
    const bool tail = active && ((lane == 63) || (snext != s));
    if (tail) {
        float* bp = ws + s;
        gadd(bp +  0 * NC, t0);  gadd(bp +  1 * NC, t1);
        gadd(bp +  2 * NC, t2);  gadd(bp +  3 * NC, t3);
        gadd(bp +  4 * NC, t4);  gadd(bp +  5 * NC, t5);
        gadd(bp +  6 * NC, t6);  gadd(bp +  7 * NC, t7);
        gadd(bp +  8 * NC, t8);  gadd(bp +  9 * NC, t9);
        gadd(bp + 10 * NC, t10); gadd(bp + 11 * NC, t11);
        gadd(bp + 12 * NC, t12); gadd(bp + 13 * NC, t13);
    }
}

__global__ __launch_bounds__(256) void cluster_kernel(
    const float* __restrict__ ws,
    const float* __restrict__ Wc1,
    const float* __restrict__ bc1,
    const float* __restrict__ Wc2,
    const float* __restrict__ bc2,
    float* __restrict__ out,
    float* __restrict__ gsum)
{
    const int c = blockIdx.x * 256 + threadIdx.x;

    const float cnt  = ws[c];
    const float wsum = ws[NC + c];
    float sA[4], swA[4], sA2[4];
    #pragma unroll
    for (int d = 0; d < 4; ++d) {
        sA[d]  = ws[(2 + d) * NC + c];
        swA[d] = ws[(6 + d) * NC + c];
        sA2[d] = ws[(10 + d) * NC + c];
    }
    const float safe_cnt = fmaxf(cnt, 1.0f);

    float agg[4];
    if (wsum > 0.0f) {
        const float inv = 1.0f / fmaxf(wsum, 1e-30f);
        #pragma unroll
        for (int d = 0; d < 4; ++d) agg[d] = swA[d] * inv;
    } else {
        const float inv = 1.0f / safe_cnt;
        #pragma unroll
        for (int d = 0; d < 4; ++d) agg[d] = sA[d] * inv;
    }

    float sq = 0.0f;
    #pragma unroll
    for (int d = 0; d < 4; ++d) {
        const float mean = sA[d] / safe_cnt;
        const float s2 = sA2[d] - 2.0f * mean * sA[d] + cnt * mean * mean;
        sq += fmaxf(s2, 0.0f);
    }
    const float var = (cnt >= 2.0f) ? (sq * 0.25f) / fmaxf(cnt - 1.0f, 1.0f) : 0.0f;
    const float phi_c = 1.0f - fminf(1.0f, var * 2.0f);
    const float coh = 1.0f - var;

    float feats[7] = { agg[0], agg[1], agg[2], agg[3],
                       phi_c, coh, fminf(1.0f, cnt * 0.05f) };

    float t = bc2[0];
    #pragma unroll
    for (int j = 0; j < 32; ++j) {
        float hj = bc1[j];
        #pragma unroll
        for (int k = 0; k < 7; ++k)
            hj = __builtin_fmaf(feats[k], Wc1[k * 32 + j], hj);
        t += fmaxf(hj, 0.0f) * Wc2[j];
    }
    const float basec = sigmoidf_(t);
    const float impc = fminf(fmaxf(basec * phi_c, 0.01f), 1.0f);
    const bool valid = cnt > 0.0f;
    const float wc = valid ? impc * cnt : 0.0f;

    // outputs
    #pragma unroll
    for (int d = 0; d < 4; ++d) out[c * 4 + d] = agg[d];
    out[NC * 4 + c] = phi_c;
    out[NC * 5 + c] = coh;

    // global partial sums: wc_sum, nvalid, wc*agg[d], valid*agg[d]
    float r[10];
    r[0] = wc;
    r[1] = valid ? 1.0f : 0.0f;
    #pragma unroll
    for (int d = 0; d < 4; ++d) r[2 + d] = wc * agg[d];
    #pragma unroll
    for (int d = 0; d < 4; ++d) r[6 + d] = valid ? agg[d] : 0.0f;

    #pragma unroll
    for (int off = 32; off > 0; off >>= 1) {
        #pragma unroll
        for (int i = 0; i < 10; ++i) r[i] += __shfl_down(r[i], off);
    }
    if ((threadIdx.x & 63) == 0) {
        #pragma unroll
        for (int i = 0; i < 10; ++i) gadd(&gsum[i], r[i]);
    }
}

__global__ void finalize_kernel(const float* __restrict__ gsum,
                                float* __restrict__ out)
{
    if (threadIdx.x == 0 && blockIdx.x == 0) {
        const float wcs = gsum[0];
        const float nv = fmaxf(gsum[1], 1.0f);
        #pragma unroll
        for (int d = 0; d < 4; ++d) {
            const float num = (wcs > 0.0f) ? gsum[2 + d] / fmaxf(wcs, 1e-30f)
                                           : gsum[6 + d] / nv;
            out[NC * 6 + d] = num;
        }
    }
}

extern "C" void kernel_launch(void* const* d_in, const int* in_sizes, int n_in,
                              void* d_out, int out_size, void* d_ws, size_t ws_size,
                              hipStream_t stream) {
    const float* cell_state = (const float*)d_in[0];
    const float* arch_state = (const float*)d_in[1];
    const float* energy     = (const float*)d_in[2];
    const float* phi_local  = (const float*)d_in[3];
    const float* W1  = (const float*)d_in[4];
    const float* b1  = (const float*)d_in[5];
    const float* W2  = (const float*)d_in[6];
    const float* b2  = (const float*)d_in[7];
    const float* Wc1 = (const float*)d_in[8];
    const float* bc1 = (const float*)d_in[9];
    const float* Wc2 = (const float*)d_in[10];
    const float* bc2 = (const float*)d_in[11];
    const int* seg   = (const int*)d_in[12];

    const int n = in_sizes[2];  // energy is [N]
    float* ws = (float*)d_ws;
    float* out = (float*)d_out;

    // zero accumulators (d_ws is poisoned, never re-poisoned between replays)
    const size_t ws_floats = (size_t)14 * NC + 16;
    hipMemsetAsync(d_ws, 0, ws_floats * sizeof(float), stream);

    const int nb = (n + 255) / 256;
    cell_kernel<<<nb, 256, 0, stream>>>(cell_state, arch_state, energy, phi_local,
                                        W1, b1, W2, b2, seg, ws, n);
    cluster_kernel<<<NC / 256, 256, 0, stream>>>(ws, Wc1, bc1, Wc2, bc2,
                                                 out, ws + (size_t)14 * NC);
    finalize_kernel<<<1, 64, 0, stream>>>(ws + (size_t)14 * NC, out);
}

// Round 4
// 103.673 us; speedup vs baseline: 55.6949x; 1.3169x over previous
//
#include <hip/hip_runtime.h>
#include <hip/hip_bf16.h>

// Problem constants (fixed by the reference file)
#define NC 8192      // n_clusters
#define SDIM 32
#define ADIM 4
#define XDIM 36      // SD + A
#define HDIM 64
// Workspace layout (floats):
//   [0*NC .. 1*NC)   counts
//   [1*NC .. 2*NC)   wsum
//   [(2+d)*NC ...)   sum arch_state[d]        d=0..3
//   [(6+d)*NC ...)   sum w*arch_state[d]
//   [(10+d)*NC ...)  sum arch_state[d]^2
//   [14*NC .. +10)   global sums

typedef _Float16 half8 __attribute__((ext_vector_type(8)));
typedef float f32x4 __attribute__((ext_vector_type(4)));

__device__ __forceinline__ float sigmoidf_(float t) {
    return 1.0f / (1.0f + __expf(-t));
}

// Native HW fp32 atomic (global_atomic_add_f32), not the default CAS loop.
__device__ __forceinline__ void gadd(float* p, float v) {
    __hip_atomic_fetch_add(p, v, __ATOMIC_RELAXED, __HIP_MEMORY_SCOPE_AGENT);
}

// MFMA-based cell stage. Per wave: 64 cells as 4 M-tiles of 16.
// x (K=36) padded to K=64 -> 2 K-steps of mfma_f32_16x16x32_f16.
// fp16 inputs (10-bit mantissa), f32 accumulate: adds ~1e-3 output error
// vs the 1.86e-2 threshold. W1 fragments live in VGPRs; no LDS.
// Fragment layouts (AMD matrix calc, m89/m91-verified family):
//   A: row=lane&15, k=(lane>>4)*8+j   B: col=lane&15, k=(lane>>4)*8+j
//   C: col=lane&15, row=(lane>>4)*4+reg
__global__ __launch_bounds__(256, 4) void cell_kernel(
    const float* __restrict__ cell_state,
    const float* __restrict__ arch_state,
    const float* __restrict__ energy,
    const float* __restrict__ phi_local,
    const float* __restrict__ W1,
    const float* __restrict__ b1,
    const float* __restrict__ W2,
    const float* __restrict__ b2,
    const int*   __restrict__ seg_ids,
    float* __restrict__ ws,
    int n)
{
    const int tid  = threadIdx.x;
    const int lane = tid & 63;
    const int l15  = lane & 15;
    const int lg   = lane >> 4;          // 0..3
    const int wave_base = blockIdx.x * 256 + (tid >> 6) * 64;

    // ---- B fragments: W1 (36x64) padded to K=64, 4 N-tiles x 2 K-steps ----
    half8 bf[4][2];
    #pragma unroll
    for (int nt = 0; nt < 4; ++nt) {
        #pragma unroll
        for (int s = 0; s < 2; ++s) {
            half8 v = {};
            #pragma unroll
            for (int jj = 0; jj < 8; ++jj) {
                const int k = 32 * s + lg * 8 + jj;
                const float wv = (k < XDIM) ? W1[k * HDIM + 16 * nt + l15] : 0.0f;
                v[jj] = (_Float16)wv;
            }
            bf[nt][s] = v;
        }
    }
    float b1v[4], w2v[4];
    #pragma unroll
    for (int nt = 0; nt < 4; ++nt) {
        b1v[nt] = b1[16 * nt + l15];
        w2v[nt] = W2[16 * nt + l15];
    }
    const float sb2 = b2[0];

    // ---- 4 M-tiles of 16 cells; after each, lanes with lg==t grab their acc ----
    float acc = 0.0f;
    #pragma unroll
    for (int t = 0; t < 4; ++t) {
        int crow = wave_base + 16 * t + l15;
        if (crow >= n) crow = n - 1;

        // A fragment, K-step 0: cell_state[crow][lg*8 .. lg*8+7]
        const float* cp = cell_state + (size_t)crow * SDIM + lg * 8;
        const float4 f0 = *reinterpret_cast<const float4*>(cp);
        const float4 f1 = *reinterpret_cast<const float4*>(cp + 4);
        half8 a0;
        a0[0] = (_Float16)f0.x; a0[1] = (_Float16)f0.y;
        a0[2] = (_Float16)f0.z; a0[3] = (_Float16)f0.w;
        a0[4] = (_Float16)f1.x; a0[5] = (_Float16)f1.y;
        a0[6] = (_Float16)f1.z; a0[7] = (_Float16)f1.w;

        // A fragment, K-step 1: k=32..35 -> arch_state, rest zero
        half8 a1 = {};
        if (lg == 0) {
            const float4 a4 = reinterpret_cast<const float4*>(arch_state)[crow];
            a1[0] = (_Float16)a4.x; a1[1] = (_Float16)a4.y;
            a1[2] = (_Float16)a4.z; a1[3] = (_Float16)a4.w;
        }

        f32x4 c[4];
        #pragma unroll
        for (int nt = 0; nt < 4; ++nt) {
            c[nt] = f32x4{0.f, 0.f, 0.f, 0.f};
            c[nt] = __builtin_amdgcn_mfma_f32_16x16x32_f16(a0, bf[nt][0], c[nt], 0, 0, 0);
            c[nt] = __builtin_amdgcn_mfma_f32_16x16x32_f16(a1, bf[nt][1], c[nt], 0, 0, 0);
        }

        // layer 2: per-lane partial over this lane's 4 columns, then butterfly
        float pq[4];
        #pragma unroll
        for (int q = 0; q < 4; ++q) {
            float sres = 0.0f;
            #pragma unroll
            for (int nt = 0; nt < 4; ++nt)
                sres = __builtin_fmaf(fmaxf(c[nt][q] + b1v[nt], 0.0f), w2v[nt], sres);
            pq[q] = sres;
        }
        #pragma unroll
        for (int msk = 1; msk < 16; msk <<= 1) {
            #pragma unroll
            for (int q = 0; q < 4; ++q) pq[q] += __shfl_xor(pq[q], msk);
        }
        // lanes in group g hold rows 4g..4g+3 (regs 0..3).
        // lane l wants row r=l15 (of its own tile t==lg): src group = r>>2.
        const int src = (l15 >> 2) * 16;
        const float s0 = __shfl(pq[0], src);
        const float s1 = __shfl(pq[1], src);
        const float s2 = __shfl(pq[2], src);
        const float s3 = __shfl(pq[3], src);
        const int rq = l15 & 3;
        const float sel = (rq == 0) ? s0 : (rq == 1) ? s1 : (rq == 2) ? s2 : s3;
        if (lg == t) acc = sel;
    }
    acc += sb2;
    const float base = sigmoidf_(acc);

    // ---- per-lane cell = wave_base + lane (coalesced), scan + atomics ----
    const int gid = blockIdx.x * 256 + tid;
    const bool active = gid < n;
    const int lid = active ? gid : (n - 1);

    const float e = energy[lid];
    const float p = phi_local[lid];
    int s = active ? seg_ids[lid] : -1;
    const float4 av = reinterpret_cast<const float4*>(arch_state)[lid];

    const float ep = e * p;
    const float imp = fminf(fmaxf(base * ep, 0.01f), 1.0f);
    const float m = active ? 1.0f : 0.0f;
    const float w = imp * ep * m;

    float t0 = m,          t1 = w;
    float t2 = m * av.x,   t3 = m * av.y,   t4 = m * av.z,   t5 = m * av.w;
    float t6 = w * av.x,   t7 = w * av.y,   t8 = w * av.z,   t9 = w * av.w;
    float t10 = m * av.x * av.x, t11 = m * av.y * av.y;
    float t12 = m * av.z * av.z, t13 = m * av.w * av.w;

#define ALL_T(F) F(t0) F(t1) F(t2) F(t3) F(t4) F(t5) F(t6) \
                 F(t7) F(t8) F(t9) F(t10) F(t11) F(t12) F(t13)
#define SCAN_ONE(V) { float u_ = __shfl_up(V, off_); if (da_) V += u_; }
#define SCAN_STEP(OFF) { const int off_ = OFF; \
    const int su_ = __shfl_up(s, off_); \
    const bool da_ = (lane >= off_) && (su_ == s); \
    ALL_T(SCAN_ONE) }

    SCAN_STEP(1); SCAN_STEP(2); SCAN_STEP(4);
    SCAN_STEP(8); SCAN_STEP(16); SCAN_STEP(32);

    const int snext = __shfl_down(s, 1);
    const bool tail = active && ((lane == 63) || (snext != s));
    if (tail) {
        float* bp = ws + s;
        gadd(bp +  0 * NC, t0);  gadd(bp +  1 * NC, t1);
        gadd(bp +  2 * NC, t2);  gadd(bp +  3 * NC, t3);
        gadd(bp +  4 * NC, t4);  gadd(bp +  5 * NC, t5);
        gadd(bp +  6 * NC, t6);  gadd(bp +  7 * NC, t7);
        gadd(bp +  8 * NC, t8);  gadd(bp +  9 * NC, t9);
        gadd(bp + 10 * NC, t10); gadd(bp + 11 * NC, t11);
        gadd(bp + 12 * NC, t12); gadd(bp + 13 * NC, t13);
    }
}

__global__ __launch_bounds__(256) void cluster_kernel(
    const float* __restrict__ ws,
    const float* __restrict__ Wc1,
    const float* __restrict__ bc1,
    const float* __restrict__ Wc2,
    const float* __restrict__ bc2,
    float* __restrict__ out,
    float* __restrict__ gsum)
{
    const int c = blockIdx.x * 256 + threadIdx.x;

    const float cnt  = ws[c];
    const float wsum = ws[NC + c];
    float sA[4], swA[4], sA2[4];
    #pragma unroll
    for (int d = 0; d < 4; ++d) {
        sA[d]  = ws[(2 + d) * NC + c];
        swA[d] = ws[(6 + d) * NC + c];
        sA2[d] = ws[(10 + d) * NC + c];
    }
    const float safe_cnt = fmaxf(cnt, 1.0f);

    float agg[4];
    if (wsum > 0.0f) {
        const float inv = 1.0f / fmaxf(wsum, 1e-30f);
        #pragma unroll
        for (int d = 0; d < 4; ++d) agg[d] = swA[d] * inv;
    } else {
        const float inv = 1.0f / safe_cnt;
        #pragma unroll
        for (int d = 0; d < 4; ++d) agg[d] = sA[d] * inv;
    }

    float sq = 0.0f;
    #pragma unroll
    for (int d = 0; d < 4; ++d) {
        const float mean = sA[d] / safe_cnt;
        const float s2 = sA2[d] - 2.0f * mean * sA[d] + cnt * mean * mean;
        sq += fmaxf(s2, 0.0f);
    }
    const float var = (cnt >= 2.0f) ? (sq * 0.25f) / fmaxf(cnt - 1.0f, 1.0f) : 0.0f;
    const float phi_c = 1.0f - fminf(1.0f, var * 2.0f);
    const float coh = 1.0f - var;

    float feats[7] = { agg[0], agg[1], agg[2], agg[3],
                       phi_c, coh, fminf(1.0f, cnt * 0.05f) };

    float t = bc2[0];
    #pragma unroll
    for (int j = 0; j < 32; ++j) {
        float hj = bc1[j];
        #pragma unroll
        for (int k = 0; k < 7; ++k)
            hj = __builtin_fmaf(feats[k], Wc1[k * 32 + j], hj);
        t += fmaxf(hj, 0.0f) * Wc2[j];
    }
    const float basec = sigmoidf_(t);
    const float impc = fminf(fmaxf(basec * phi_c, 0.01f), 1.0f);
    const bool valid = cnt > 0.0f;
    const float wc = valid ? impc * cnt : 0.0f;

    // outputs
    #pragma unroll
    for (int d = 0; d < 4; ++d) out[c * 4 + d] = agg[d];
    out[NC * 4 + c] = phi_c;
    out[NC * 5 + c] = coh;

    // global partial sums: wc_sum, nvalid, wc*agg[d], valid*agg[d]
    float r[10];
    r[0] = wc;
    r[1] = valid ? 1.0f : 0.0f;
    #pragma unroll
    for (int d = 0; d < 4; ++d) r[2 + d] = wc * agg[d];
    #pragma unroll
    for (int d = 0; d < 4; ++d) r[6 + d] = valid ? agg[d] : 0.0f;

    #pragma unroll
    for (int off = 32; off > 0; off >>= 1) {
        #pragma unroll
        for (int i = 0; i < 10; ++i) r[i] += __shfl_down(r[i], off);
    }
    if ((threadIdx.x & 63) == 0) {
        #pragma unroll
        for (int i = 0; i < 10; ++i) gadd(&gsum[i], r[i]);
    }
}

__global__ void finalize_kernel(const float* __restrict__ gsum,
                                float* __restrict__ out)
{
    if (threadIdx.x == 0 && blockIdx.x == 0) {
        const float wcs = gsum[0];
        const float nv = fmaxf(gsum[1], 1.0f);
        #pragma unroll
        for (int d = 0; d < 4; ++d) {
            const float num = (wcs > 0.0f) ? gsum[2 + d] / fmaxf(wcs, 1e-30f)
                                           : gsum[6 + d] / nv;
            out[NC * 6 + d] = num;
        }
    }
}

extern "C" void kernel_launch(void* const* d_in, const int* in_sizes, int n_in,
                              void* d_out, int out_size, void* d_ws, size_t ws_size,
                              hipStream_t stream) {
    const float* cell_state = (const float*)d_in[0];
    const float* arch_state = (const float*)d_in[1];
    const float* energy     = (const float*)d_in[2];
    const float* phi_local  = (const float*)d_in[3];
    const float* W1  = (const float*)d_in[4];
    const float* b1  = (const float*)d_in[5];
    const float* W2  = (const float*)d_in[6];
    const float* b2  = (const float*)d_in[7];
    const float* Wc1 = (const float*)d_in[8];
    const float* bc1 = (const float*)d_in[9];
    const float* Wc2 = (const float*)d_in[10];
    const float* bc2 = (const float*)d_in[11];
    const int* seg   = (const int*)d_in[12];

    const int n = in_sizes[2];  // energy is [N]
    float* ws = (float*)d_ws;
    float* out = (float*)d_out;

    // zero accumulators (d_ws is poisoned, never re-poisoned between replays)
    const size_t ws_floats = (size_t)14 * NC + 16;
    hipMemsetAsync(d_ws, 0, ws_floats * sizeof(float), stream);

    const int nb = (n + 255) / 256;
    cell_kernel<<<nb, 256, 0, stream>>>(cell_state, arch_state, energy, phi_local,
                                        W1, b1, W2, b2, seg, ws, n);
    cluster_kernel<<<NC / 256, 256, 0, stream>>>(ws, Wc1, bc1, Wc2, bc2,
                                                 out, ws + (size_t)14 * NC);
    finalize_kernel<<<1, 64, 0, stream>>>(ws + (size_t)14 * NC, out);
}

// Round 5
// 84.636 us; speedup vs baseline: 68.2222x; 1.2249x over previous
//
#include <hip/hip_runtime.h>
#include <hip/hip_bf16.h>

// Problem constants (fixed by the reference file)
#define NC 8192      // n_clusters
#define SDIM 32
#define ADIM 4
#define XDIM 36      // SD + A
#define HDIM 64
#define CPT 2        // 64-cell chunks per wave
// Workspace layout (floats):
//   [0*NC .. 1*NC)   counts
//   [1*NC .. 2*NC)   wsum
//   [(2+d)*NC ...)   sum arch_state[d]        d=0..3
//   [(6+d)*NC ...)   sum w*arch_state[d]
//   [(10+d)*NC ...)  sum arch_state[d]^2
//   [14*NC .. +10)   global sums

typedef _Float16 half8 __attribute__((ext_vector_type(8)));
typedef float f32x4 __attribute__((ext_vector_type(4)));

__device__ __forceinline__ float sigmoidf_(float t) {
    return 1.0f / (1.0f + __expf(-t));
}

// Native HW fp32 atomic (global_atomic_add_f32), not the default CAS loop.
__device__ __forceinline__ void gadd(float* p, float v) {
    __hip_atomic_fetch_add(p, v, __ATOMIC_RELAXED, __HIP_MEMORY_SCOPE_AGENT);
}

// Operand-SWAPPED MFMA cell stage: D = W1^T-frag x x-frag  ->  D = h^T with
//   col = cell = lane&15, row = h_local = (lane>>4)*4 + reg.
// Each lane then holds 16 h values (4 n-tiles x 4 regs) of ONE cell, so the
// layer-2 reduction (relu(h).W2) is lane-local + 2 shfl_xor (over lane>>4
// groups) instead of a 20-shfl butterfly per tile.
// b1 is folded into K: x[36]=1, A[h][36]=b1[h] (K padded 36->64 anyway).
// Fragment layouts per guide (m89/m91-verified family):
//   A: row=lane&15, k=(lane>>4)*8+j   B: col=lane&15, k=(lane>>4)*8+j
//   D: col=lane&15, row=(lane>>4)*4+reg
__global__ __launch_bounds__(256, 4) void cell_kernel(
    const float* __restrict__ cell_state,
    const float* __restrict__ arch_state,
    const float* __restrict__ energy,
    const float* __restrict__ phi_local,
    const float* __restrict__ W1,
    const float* __restrict__ b1,
    const float* __restrict__ W2,
    const float* __restrict__ b2,
    const int*   __restrict__ seg_ids,
    float* __restrict__ ws,
    int n)
{
    const int tid  = threadIdx.x;
    const int lane = tid & 63;
    const int l15  = lane & 15;
    const int lg   = lane >> 4;          // 0..3

    // ---- A fragments: W1^T (h x K), K=36(+bias row 36) padded to 64 ----
    // af[nt][s]: h = 16*nt + l15 (row), k = 32*s + lg*8 + j
    half8 af[4][2];
    #pragma unroll
    for (int nt = 0; nt < 4; ++nt) {
        #pragma unroll
        for (int s = 0; s < 2; ++s) {
            half8 v = {};
            #pragma unroll
            for (int jj = 0; jj < 8; ++jj) {
                const int k = 32 * s + lg * 8 + jj;
                float wv = 0.0f;
                if (k < XDIM)       wv = W1[k * HDIM + 16 * nt + l15];
                else if (k == XDIM) wv = b1[16 * nt + l15];   // bias row
                v[jj] = (_Float16)wv;
            }
            af[nt][s] = v;
        }
    }
    // w2v[nt*4+q] = W2[h] for h = 16*nt + lg*4 + q (this lane's 16 h rows)
    float w2v[16];
    #pragma unroll
    for (int nt = 0; nt < 4; ++nt)
        #pragma unroll
        for (int q = 0; q < 4; ++q)
            w2v[nt * 4 + q] = W2[16 * nt + lg * 4 + q];
    const float sb2 = b2[0];

    #pragma unroll 1
    for (int ch = 0; ch < CPT; ++ch) {
        const int chunk_base = blockIdx.x * (256 * CPT) + (tid >> 6) * (64 * CPT) + ch * 64;

        // ---- 4 M-tiles of 16 cells; lane keeps result of its own tile lg ----
        float acc = 0.0f;
        #pragma unroll
        for (int t = 0; t < 4; ++t) {
            int crow = chunk_base + 16 * t + l15;
            if (crow >= n) crow = n - 1;

            // B fragment step 0: x[cell=l15][k=lg*8..+7] from cell_state
            const float* cp = cell_state + (size_t)crow * SDIM + lg * 8;
            const float4 f0 = *reinterpret_cast<const float4*>(cp);
            const float4 f1 = *reinterpret_cast<const float4*>(cp + 4);
            half8 x0;
            x0[0] = (_Float16)f0.x; x0[1] = (_Float16)f0.y;
            x0[2] = (_Float16)f0.z; x0[3] = (_Float16)f0.w;
            x0[4] = (_Float16)f1.x; x0[5] = (_Float16)f1.y;
            x0[6] = (_Float16)f1.z; x0[7] = (_Float16)f1.w;

            // B fragment step 1: k=32..35 -> arch, k=36 -> 1.0 (bias), rest 0
            half8 x1 = {};
            if (lg == 0) {
                const float4 a4 = reinterpret_cast<const float4*>(arch_state)[crow];
                x1[0] = (_Float16)a4.x; x1[1] = (_Float16)a4.y;
                x1[2] = (_Float16)a4.z; x1[3] = (_Float16)a4.w;
                x1[4] = (_Float16)1.0f;      // bias input
            }

            // D = h^T: lane holds h = 16*nt + lg*4 + q for cell l15
            float pq = 0.0f;
            #pragma unroll
            for (int nt = 0; nt < 4; ++nt) {
                f32x4 c = f32x4{0.f, 0.f, 0.f, 0.f};
                c = __builtin_amdgcn_mfma_f32_16x16x32_f16(af[nt][0], x0, c, 0, 0, 0);
                c = __builtin_amdgcn_mfma_f32_16x16x32_f16(af[nt][1], x1, c, 0, 0, 0);
                #pragma unroll
                for (int q = 0; q < 4; ++q)
                    pq = __builtin_fmaf(fmaxf(c[q], 0.0f), w2v[nt * 4 + q], pq);
            }
            // reduce over the 4 lane-groups (same cell l15)
            pq += __shfl_xor(pq, 16);
            pq += __shfl_xor(pq, 32);
            if (lg == t) acc = pq;
        }
        acc += sb2;
        const float base = sigmoidf_(acc);

        // ---- per-lane cell = chunk_base + lane (coalesced), scan + atomics ----
        const int gid = chunk_base + lane;
        const bool active = gid < n;
        const int lid = active ? gid : (n - 1);

        const float e = energy[lid];
        const float p = phi_local[lid];
        int s = active ? seg_ids[lid] : -1;
        const float4 av = reinterpret_cast<const float4*>(arch_state)[lid];

        const float ep = e * p;
        const float imp = fminf(fmaxf(base * ep, 0.01f), 1.0f);
        const float m = active ? 1.0f : 0.0f;
        const float w = imp * ep * m;

        float t0 = m,          t1 = w;
        float t2 = m * av.x,   t3 = m * av.y,   t4 = m * av.z,   t5 = m * av.w;
        float t6 = w * av.x,   t7 = w * av.y,   t8 = w * av.z,   t9 = w * av.w;
        float t10 = m * av.x * av.x, t11 = m * av.y * av.y;
        float t12 = m * av.z * av.z, t13 = m * av.w * av.w;

#define ALL_T(F) F(t0) F(t1) F(t2) F(t3) F(t4) F(t5) F(t6) \
                 F(t7) F(t8) F(t9) F(t10) F(t11) F(t12) F(t13)
#define SCAN_ONE(V) { float u_ = __shfl_up(V, off_); if (da_) V += u_; }
#define SCAN_STEP(OFF) { const int off_ = OFF; \
    const int su_ = __shfl_up(s, off_); \
    const bool da_ = (lane >= off_) && (su_ == s); \
    ALL_T(SCAN_ONE) }

        SCAN_STEP(1); SCAN_STEP(2); SCAN_STEP(4);
        SCAN_STEP(8); SCAN_STEP(16); SCAN_STEP(32);

        const int snext = __shfl_down(s, 1);
        const bool tail = active && ((lane == 63) || (snext != s));
        if (tail) {
            float* bp = ws + s;
            gadd(bp +  0 * NC, t0);  gadd(bp +  1 * NC, t1);
            gadd(bp +  2 * NC, t2);  gadd(bp +  3 * NC, t3);
            gadd(bp +  4 * NC, t4);  gadd(bp +  5 * NC, t5);
            gadd(bp +  6 * NC, t6);  gadd(bp +  7 * NC, t7);
            gadd(bp +  8 * NC, t8);  gadd(bp +  9 * NC, t9);
            gadd(bp + 10 * NC, t10); gadd(bp + 11 * NC, t11);
            gadd(bp + 12 * NC, t12); gadd(bp + 13 * NC, t13);
        }
    }
}

__global__ __launch_bounds__(256) void cluster_kernel(
    const float* __restrict__ ws,
    const float* __restrict__ Wc1,
    const float* __restrict__ bc1,
    const float* __restrict__ Wc2,
    const float* __restrict__ bc2,
    float* __restrict__ out,
    float* __restrict__ gsum)
{
    const int c = blockIdx.x * 256 + threadIdx.x;

    const float cnt  = ws[c];
    const float wsum = ws[NC + c];
    float sA[4], swA[4], sA2[4];
    #pragma unroll
    for (int d = 0; d < 4; ++d) {
        sA[d]  = ws[(2 + d) * NC + c];
        swA[d] = ws[(6 + d) * NC + c];
        sA2[d] = ws[(10 + d) * NC + c];
    }
    const float safe_cnt = fmaxf(cnt, 1.0f);

    float agg[4];
    if (wsum > 0.0f) {
        const float inv = 1.0f / fmaxf(wsum, 1e-30f);
        #pragma unroll
        for (int d = 0; d < 4; ++d) agg[d] = swA[d] * inv;
    } else {
        const float inv = 1.0f / safe_cnt;
        #pragma unroll
        for (int d = 0; d < 4; ++d) agg[d] = sA[d] * inv;
    }

    float sq = 0.0f;
    #pragma unroll
    for (int d = 0; d < 4; ++d) {
        const float mean = sA[d] / safe_cnt;
        const float s2 = sA2[d] - 2.0f * mean * sA[d] + cnt * mean * mean;
        sq += fmaxf(s2, 0.0f);
    }
    const float var = (cnt >= 2.0f) ? (sq * 0.25f) / fmaxf(cnt - 1.0f, 1.0f) : 0.0f;
    const float phi_c = 1.0f - fminf(1.0f, var * 2.0f);
    const float coh = 1.0f - var;

    float feats[7] = { agg[0], agg[1], agg[2], agg[3],
                       phi_c, coh, fminf(1.0f, cnt * 0.05f) };

    float t = bc2[0];
    #pragma unroll
    for (int j = 0; j < 32; ++j) {
        float hj = bc1[j];
        #pragma unroll
        for (int k = 0; k < 7; ++k)
            hj = __builtin_fmaf(feats[k], Wc1[k * 32 + j], hj);
        t += fmaxf(hj, 0.0f) * Wc2[j];
    }
    const float basec = sigmoidf_(t);
    const float impc = fminf(fmaxf(basec * phi_c, 0.01f), 1.0f);
    const bool valid = cnt > 0.0f;
    const float wc = valid ? impc * cnt : 0.0f;

    // outputs
    #pragma unroll
    for (int d = 0; d < 4; ++d) out[c * 4 + d] = agg[d];
    out[NC * 4 + c] = phi_c;
    out[NC * 5 + c] = coh;

    // global partial sums: wc_sum, nvalid, wc*agg[d], valid*agg[d]
    float r[10];
    r[0] = wc;
    r[1] = valid ? 1.0f : 0.0f;
    #pragma unroll
    for (int d = 0; d < 4; ++d) r[2 + d] = wc * agg[d];
    #pragma unroll
    for (int d = 0; d < 4; ++d) r[6 + d] = valid ? agg[d] : 0.0f;

    #pragma unroll
    for (int off = 32; off > 0; off >>= 1) {
        #pragma unroll
        for (int i = 0; i < 10; ++i) r[i] += __shfl_down(r[i], off);
    }
    if ((threadIdx.x & 63) == 0) {
        #pragma unroll
        for (int i = 0; i < 10; ++i) gadd(&gsum[i], r[i]);
    }
}

__global__ void finalize_kernel(const float* __restrict__ gsum,
                                float* __restrict__ out)
{
    if (threadIdx.x == 0 && blockIdx.x == 0) {
        const float wcs = gsum[0];
        const float nv = fmaxf(gsum[1], 1.0f);
        #pragma unroll
        for (int d = 0; d < 4; ++d) {
            const float num = (wcs > 0.0f) ? gsum[2 + d] / fmaxf(wcs, 1e-30f)
                                           : gsum[6 + d] / nv;
            out[NC * 6 + d] = num;
        }
    }
}

extern "C" void kernel_launch(void* const* d_in, const int* in_sizes, int n_in,
                              void* d_out, int out_size, void* d_ws, size_t ws_size,
                              hipStream_t stream) {
    const float* cell_state = (const float*)d_in[0];
    const float* arch_state = (const float*)d_in[1];
    const float* energy     = (const float*)d_in[2];
    const float* phi_local  = (const float*)d_in[3];
    const float* W1  = (const float*)d_in[4];
    const float* b1  = (const float*)d_in[5];
    const float* W2  = (const float*)d_in[6];
    const float* b2  = (const float*)d_in[7];
    const float* Wc1 = (const float*)d_in[8];
    const float* bc1 = (const float*)d_in[9];
    const float* Wc2 = (const float*)d_in[10];
    const float* bc2 = (const float*)d_in[11];
    const int* seg   = (const int*)d_in[12];

    const int n = in_sizes[2];  // energy is [N]
    float* ws = (float*)d_ws;
    float* out = (float*)d_out;

    // zero accumulators (d_ws is poisoned, never re-poisoned between replays)
    const size_t ws_floats = (size_t)14 * NC + 16;
    hipMemsetAsync(d_ws, 0, ws_floats * sizeof(float), stream);

    const int cells_per_block = 256 * CPT;
    const int nb = (n + cells_per_block - 1) / cells_per_block;
    cell_kernel<<<nb, 256, 0, stream>>>(cell_state, arch_state, energy, phi_local,
                                        W1, b1, W2, b2, seg, ws, n);
    cluster_kernel<<<NC / 256, 256, 0, stream>>>(ws, Wc1, bc1, Wc2, bc2,
                                                 out, ws + (size_t)14 * NC);
    finalize_kernel<<<1, 64, 0, stream>>>(ws + (size_t)14 * NC, out);
}

// Round 7
// 75.527 us; speedup vs baseline: 76.4501x; 1.1206x over previous
//
#include <hip/hip_runtime.h>
#include <hip/hip_bf16.h>

// Problem constants (fixed by the reference file)
#define NC 8192      // n_clusters
#define SDIM 32
#define ADIM 4
#define XDIM 36      // SD + A
#define HDIM 64
#define CPT 2        // 64-cell chunks per wave in mlp_kernel
// Workspace layout:
//   float w_arr[n]                          (cell weights from MLP)
//   int   startx[NC], endx[NC]              (cluster ranges; memset 0 -> empty ok)
//   float ws2[10*NC]                        (per-cluster global partials:
//        k=0 wc, k=1 valid, k=2..5 wc*agg[d], k=6..9 valid*agg[d])

typedef _Float16 half8 __attribute__((ext_vector_type(8)));
typedef float f32x4 __attribute__((ext_vector_type(4)));

__device__ __forceinline__ float sigmoidf_(float t) {
    return 1.0f / (1.0f + __expf(-t));
}

// ---- cluster range discovery on sorted segment_ids ----
__global__ __launch_bounds__(256) void bounds_kernel(
    const int* __restrict__ seg, int* __restrict__ startx,
    int* __restrict__ endx, int n)
{
    const int i = blockIdx.x * 256 + threadIdx.x;
    if (i >= n) return;
    const int s = seg[i];
    if (i == 0 || seg[i - 1] != s) startx[s] = i;
    if (i == n - 1 || seg[i + 1] != s) endx[s] = i + 1;
}

// ---- per-cell MLP via operand-swapped MFMA (r5-verified fragments) ----
// D = W1^T-frag x x-frag: col=cell=lane&15, row=h=(lane>>4)*4+reg.
// b1 folded into K row 36. Epilogue: w[gid] store only (no scan/atomics).
__global__ __launch_bounds__(256, 4) void mlp_kernel(
    const float* __restrict__ cell_state,
    const float* __restrict__ arch_state,
    const float* __restrict__ energy,
    const float* __restrict__ phi_local,
    const float* __restrict__ W1,
    const float* __restrict__ b1,
    const float* __restrict__ W2,
    const float* __restrict__ b2,
    float* __restrict__ w_out,
    int n)
{
    const int tid  = threadIdx.x;
    const int lane = tid & 63;
    const int l15  = lane & 15;
    const int lg   = lane >> 4;          // 0..3

    // A fragments: W1^T (h x K), K=36(+bias row 36) padded to 64
    half8 af[4][2];
    #pragma unroll
    for (int nt = 0; nt < 4; ++nt) {
        #pragma unroll
        for (int s = 0; s < 2; ++s) {
            half8 v = {};
            #pragma unroll
            for (int jj = 0; jj < 8; ++jj) {
                const int k = 32 * s + lg * 8 + jj;
                float wv = 0.0f;
                if (k < XDIM)       wv = W1[k * HDIM + 16 * nt + l15];
                else if (k == XDIM) wv = b1[16 * nt + l15];   // bias row
                v[jj] = (_Float16)wv;
            }
            af[nt][s] = v;
        }
    }
    float w2v[16];
    #pragma unroll
    for (int nt = 0; nt < 4; ++nt)
        #pragma unroll
        for (int q = 0; q < 4; ++q)
            w2v[nt * 4 + q] = W2[16 * nt + lg * 4 + q];
    const float sb2 = b2[0];

    #pragma unroll 1
    for (int ch = 0; ch < CPT; ++ch) {
        const int chunk_base = blockIdx.x * (256 * CPT) + (tid >> 6) * (64 * CPT) + ch * 64;

        float acc = 0.0f;
        #pragma unroll
        for (int t = 0; t < 4; ++t) {
            int crow = chunk_base + 16 * t + l15;
            if (crow >= n) crow = n - 1;

            const float* cp = cell_state + (size_t)crow * SDIM + lg * 8;
            const float4 f0 = *reinterpret_cast<const float4*>(cp);
            const float4 f1 = *reinterpret_cast<const float4*>(cp + 4);
            half8 x0;
            x0[0] = (_Float16)f0.x; x0[1] = (_Float16)f0.y;
            x0[2] = (_Float16)f0.z; x0[3] = (_Float16)f0.w;
            x0[4] = (_Float16)f1.x; x0[5] = (_Float16)f1.y;
            x0[6] = (_Float16)f1.z; x0[7] = (_Float16)f1.w;

            half8 x1 = {};
            if (lg == 0) {
                const float4 a4 = reinterpret_cast<const float4*>(arch_state)[crow];
                x1[0] = (_Float16)a4.x; x1[1] = (_Float16)a4.y;
                x1[2] = (_Float16)a4.z; x1[3] = (_Float16)a4.w;
                x1[4] = (_Float16)1.0f;      // bias input
            }

            float pq = 0.0f;
            #pragma unroll
            for (int nt = 0; nt < 4; ++nt) {
                f32x4 c = f32x4{0.f, 0.f, 0.f, 0.f};
                c = __builtin_amdgcn_mfma_f32_16x16x32_f16(af[nt][0], x0, c, 0, 0, 0);
                c = __builtin_amdgcn_mfma_f32_16x16x32_f16(af[nt][1], x1, c, 0, 0, 0);
                #pragma unroll
                for (int q = 0; q < 4; ++q)
                    pq = __builtin_fmaf(fmaxf(c[q], 0.0f), w2v[nt * 4 + q], pq);
            }
            pq += __shfl_xor(pq, 16);
            pq += __shfl_xor(pq, 32);
            if (lg == t) acc = pq;
        }
        const float base = sigmoidf_(acc + sb2);

        const int gid = chunk_base + lane;
        if (gid < n) {
            const float ep = energy[gid] * phi_local[gid];
            const float imp = fminf(fmaxf(base * ep, 0.01f), 1.0f);
            w_out[gid] = imp * ep;
        }
    }
}

// ---- one wave per cluster: register accumulation over [start,end),
//      one butterfly, fused cluster MLP, per-cluster partial writes ----
__global__ __launch_bounds__(256) void cluster_kernel(
    const float* __restrict__ arch_state,
    const float* __restrict__ w_arr,
    const int*   __restrict__ startx,
    const int*   __restrict__ endx,
    const float* __restrict__ Wc1,
    const float* __restrict__ bc1,
    const float* __restrict__ Wc2,
    const float* __restrict__ bc2,
    float* __restrict__ out,
    float* __restrict__ ws2)
{
    const int lane = threadIdx.x & 63;
    const int c = blockIdx.x * 4 + (threadIdx.x >> 6);
    const int s0 = startx[c];
    const int e0 = endx[c];

    float pw = 0.0f;
    float pa0 = 0.f, pa1 = 0.f, pa2 = 0.f, pa3 = 0.f;
    float pw0 = 0.f, pw1 = 0.f, pw2 = 0.f, pw3 = 0.f;
    float pq0 = 0.f, pq1 = 0.f, pq2 = 0.f, pq3 = 0.f;
    const float4* arch4 = reinterpret_cast<const float4*>(arch_state);
    for (int i = s0 + lane; i < e0; i += 64) {
        const float4 a = arch4[i];
        const float wv = w_arr[i];
        pw += wv;
        pa0 += a.x; pa1 += a.y; pa2 += a.z; pa3 += a.w;
        pw0 = __builtin_fmaf(wv, a.x, pw0); pw1 = __builtin_fmaf(wv, a.y, pw1);
        pw2 = __builtin_fmaf(wv, a.z, pw2); pw3 = __builtin_fmaf(wv, a.w, pw3);
        pq0 = __builtin_fmaf(a.x, a.x, pq0); pq1 = __builtin_fmaf(a.y, a.y, pq1);
        pq2 = __builtin_fmaf(a.z, a.z, pq2); pq3 = __builtin_fmaf(a.w, a.w, pq3);
    }
#define RED13(F) F(pw) F(pa0) F(pa1) F(pa2) F(pa3) \
                 F(pw0) F(pw1) F(pw2) F(pw3) F(pq0) F(pq1) F(pq2) F(pq3)
#define BFLY(V) V += __shfl_xor(V, off_);
    #pragma unroll
    for (int off_ = 1; off_ < 64; off_ <<= 1) { RED13(BFLY) }

    const float cnt = (float)(e0 - s0);
    const float safe_cnt = fmaxf(cnt, 1.0f);
    const float wsum = pw;

    float agg[4];
    if (wsum > 0.0f) {
        const float inv = 1.0f / fmaxf(wsum, 1e-30f);
        agg[0] = pw0 * inv; agg[1] = pw1 * inv;
        agg[2] = pw2 * inv; agg[3] = pw3 * inv;
    } else {
        const float inv = 1.0f / safe_cnt;
        agg[0] = pa0 * inv; agg[1] = pa1 * inv;
        agg[2] = pa2 * inv; agg[3] = pa3 * inv;
    }

    const float sA[4]  = { pa0, pa1, pa2, pa3 };
    const float sA2[4] = { pq0, pq1, pq2, pq3 };
    float sq = 0.0f;
    #pragma unroll
    for (int d = 0; d < 4; ++d) {
        const float mean = sA[d] / safe_cnt;
        const float s2 = sA2[d] - 2.0f * mean * sA[d] + cnt * mean * mean;
        sq += fmaxf(s2, 0.0f);
    }
    const float var = (cnt >= 2.0f) ? (sq * 0.25f) / fmaxf(cnt - 1.0f, 1.0f) : 0.0f;
    const float phi_c = 1.0f - fminf(1.0f, var * 2.0f);
    const float coh = 1.0f - var;

    const float feats[7] = { agg[0], agg[1], agg[2], agg[3],
                             phi_c, coh, fminf(1.0f, cnt * 0.05f) };
    float t = bc2[0];
    #pragma unroll
    for (int j = 0; j < 32; ++j) {
        float hj = bc1[j];
        #pragma unroll
        for (int k = 0; k < 7; ++k)
            hj = __builtin_fmaf(feats[k], Wc1[k * 32 + j], hj);
        t += fmaxf(hj, 0.0f) * Wc2[j];
    }
    const float basec = sigmoidf_(t);
    const float impc = fminf(fmaxf(basec * phi_c, 0.01f), 1.0f);
    const bool valid = cnt > 0.0f;
    const float wc = valid ? impc * cnt : 0.0f;
    const float vf = valid ? 1.0f : 0.0f;

    if (lane == 0) {
        out[c * 4 + 0] = agg[0]; out[c * 4 + 1] = agg[1];
        out[c * 4 + 2] = agg[2]; out[c * 4 + 3] = agg[3];
        out[NC * 4 + c] = phi_c;
        out[NC * 5 + c] = coh;
        ws2[0 * NC + c] = wc;
        ws2[1 * NC + c] = vf;
        #pragma unroll
        for (int d = 0; d < 4; ++d) ws2[(2 + d) * NC + c] = wc * agg[d];
        #pragma unroll
        for (int d = 0; d < 4; ++d) ws2[(6 + d) * NC + c] = vf * agg[d];
    }
}

// ---- single-block reduction of the 10 per-cluster partial arrays ----
__global__ __launch_bounds__(1024) void finalize_kernel(
    const float* __restrict__ ws2, float* __restrict__ out)
{
    __shared__ float red[16][10];
    const int tid = threadIdx.x;
    const int lane = tid & 63;
    const int wv = tid >> 6;

    float r[10];
    #pragma unroll
    for (int k = 0; k < 10; ++k) r[k] = 0.0f;
    for (int c = tid; c < NC; c += 1024) {
        #pragma unroll
        for (int k = 0; k < 10; ++k) r[k] += ws2[k * NC + c];
    }
    #pragma unroll
    for (int off = 1; off < 64; off <<= 1) {
        #pragma unroll
        for (int k = 0; k < 10; ++k) r[k] += __shfl_xor(r[k], off);
    }
    if (lane == 0) {
        #pragma unroll
        for (int k = 0; k < 10; ++k) red[wv][k] = r[k];
    }
    __syncthreads();
    if (tid == 0) {
        float g[10];
        #pragma unroll
        for (int k = 0; k < 10; ++k) {
            float acc = 0.0f;
            for (int i = 0; i < 16; ++i) acc += red[i][k];
            g[k] = acc;
        }
        const float wcs = g[0];
        const float nv = fmaxf(g[1], 1.0f);
        #pragma unroll
        for (int d = 0; d < 4; ++d) {
            out[NC * 6 + d] = (wcs > 0.0f) ? g[2 + d] / fmaxf(wcs, 1e-30f)
                                           : g[6 + d] / nv;
        }
    }
}

extern "C" void kernel_launch(void* const* d_in, const int* in_sizes, int n_in,
                              void* d_out, int out_size, void* d_ws, size_t ws_size,
                              hipStream_t stream) {
    const float* cell_state = (const float*)d_in[0];
    const float* arch_state = (const float*)d_in[1];
    const float* energy     = (const float*)d_in[2];
    const float* phi_local  = (const float*)d_in[3];
    const float* W1  = (const float*)d_in[4];
    const float* b1  = (const float*)d_in[5];
    const float* W2  = (const float*)d_in[6];
    const float* b2  = (const float*)d_in[7];
    const float* Wc1 = (const float*)d_in[8];
    const float* bc1 = (const float*)d_in[9];
    const float* Wc2 = (const float*)d_in[10];
    const float* bc2 = (const float*)d_in[11];
    const int* seg   = (const int*)d_in[12];

    const int n = in_sizes[2];  // energy is [N]
    float* out = (float*)d_out;

    float* w_arr = (float*)d_ws;                  // n floats
    int* startx  = (int*)(w_arr + n);             // NC ints
    int* endx    = startx + NC;                   // NC ints
    float* ws2   = (float*)(endx + NC);           // 10*NC floats

    // zero only the bounds (empty-cluster handling); poisoned otherwise
    (void)hipMemsetAsync(startx, 0, 2 * NC * sizeof(int), stream);

    bounds_kernel<<<(n + 255) / 256, 256, 0, stream>>>(seg, startx, endx, n);

    const int cells_per_block = 256 * CPT;
    const int nb = (n + cells_per_block - 1) / cells_per_block;
    mlp_kernel<<<nb, 256, 0, stream>>>(cell_state, arch_state, energy, phi_local,
                                       W1, b1, W2, b2, w_arr, n);
    cluster_kernel<<<NC / 4, 256, 0, stream>>>(arch_state, w_arr, startx, endx,
                                               Wc1, bc1, Wc2, bc2, out, ws2);
    finalize_kernel<<<1, 1024, 0, stream>>>(ws2, out);
}